// Round 11
// baseline (188.584 us; speedup 1.0000x reference)
//
#include <hip/hip_runtime.h>
#include <hip/hip_fp16.h>

#define N_NODES 25000
#define N_EDGES 250000
#define ED 6
#define H1 64
#define H2 128
#define NBLK 977                   // ceil(250000/256)
#define K_TOT 4224                 // ush per row: 4096 (h2*xs) + 32 (b3) + 96 pad (132 ksteps)
#define W3S_USHORTS (32*K_TOT)     // 135168 = 264KB, L2-resident
#define W2S_USHORTS (H2*H1)
#define SCAN_BLOCKS 98
#define ROWB (K_TOT*2)             // 8448 bytes per w3s row

typedef float f32x4 __attribute__((ext_vector_type(4)));
typedef _Float16 f16x8 __attribute__((ext_vector_type(8)));
typedef _Float16 f16x2 __attribute__((ext_vector_type(2)));
typedef __fp16 fp16x2 __attribute__((ext_vector_type(2)));
typedef unsigned int u32x4 __attribute__((ext_vector_type(4)));
typedef unsigned int u32x2 __attribute__((ext_vector_type(2)));

union F16x8U { u32x4 u; f16x8 h; };
union F16x2U { unsigned u; f16x2 h; };
union PKU    { fp16x2 p; unsigned u; };

__device__ __forceinline__ unsigned pkrtz(float lo, float hi) {
    PKU r; r.p = __builtin_amdgcn_cvt_pkrtz(lo, hi); return r.u;
}
// d = (h.lo * x.lo, h.lo * x.hi)
__device__ __forceinline__ unsigned pk_mul_blo(unsigned h, unsigned x) {
    unsigned d;
    asm("v_pk_mul_f16 %0, %1, %2 op_sel:[0,0] op_sel_hi:[0,1]" : "=v"(d) : "v"(h), "v"(x));
    return d;
}
// d = (h.hi * x.lo, h.hi * x.hi)
__device__ __forceinline__ unsigned pk_mul_bhi(unsigned h, unsigned x) {
    unsigned d;
    asm("v_pk_mul_f16 %0, %1, %2 op_sel:[1,0] op_sel_hi:[1,1]" : "=v"(d) : "v"(h), "v"(x));
    return d;
}
__device__ __forceinline__ f32x4 mfma16(f16x8 a, f16x8 b, f32x4 c) {
    return __builtin_amdgcn_mfma_f32_16x16x32_f16(a, b, c, 0, 0, 0);
}

// ---------------- init: zero cnt + repack W3(+b3)->fp16 row-major, W2->fp16
// w3s row p (stride K_TOT) holds output o = (p&15)*2 + (p>>4) (o-interleave
// for packed epilogue stores). k' = k*32+i; [4096,4128) = b3; rest zero pad.
__global__ __launch_bounds__(256) void ecc_init(
    const float* __restrict__ W3, const float* __restrict__ b3,
    const float* __restrict__ W2,
    unsigned* __restrict__ cnt, unsigned short* __restrict__ w3s,
    unsigned short* __restrict__ w2s)
{
    int idx = blockIdx.x * 256 + threadIdx.x;
    if (idx < W3S_USHORTS) {
        int p = idx / K_TOT, kp = idx % K_TOT;
        int o = ((p & 15) << 1) + (p >> 4);
        float v = 0.f;
        if (kp < 4096)      { int k = kp >> 5, i = kp & 31; v = W3[(o * 32 + i) * 128 + k]; }
        else if (kp < 4128) { v = b3[o * 32 + (kp - 4096)]; }
        __half hv = __float2half_rn(v);
        w3s[idx] = *reinterpret_cast<unsigned short*>(&hv);
    }
    if (idx < W2S_USHORTS) {
        __half hv = __float2half_rn(W2[idx]);
        w2s[idx] = *reinterpret_cast<unsigned short*>(&hv);
    }
    if (idx < N_NODES) cnt[idx] = 0u;
}

// ---------------- sort machinery -------------------------------------------
__global__ __launch_bounds__(256) void ecc_hist(
    const int* __restrict__ dst, unsigned* __restrict__ cnt,
    unsigned* __restrict__ rank)
{
    int e = blockIdx.x * 256 + threadIdx.x;
    if (e < N_EDGES) rank[e] = atomicAdd(&cnt[dst[e]], 1u);
}

__global__ __launch_bounds__(256) void ecc_scan1(
    const unsigned* __restrict__ cnt, unsigned* __restrict__ off,
    unsigned* __restrict__ bsum)
{
    __shared__ unsigned s[256];
    const int t = threadIdx.x, i = blockIdx.x * 256 + t;
    unsigned v = (i < N_NODES) ? cnt[i] : 0u;
    s[t] = v; __syncthreads();
    #pragma unroll
    for (int d = 1; d < 256; d <<= 1) {
        unsigned add = (t >= d) ? s[t - d] : 0u;
        __syncthreads(); s[t] += add; __syncthreads();
    }
    if (i < N_NODES) off[i] = s[t] - v;
    if (t == 255) bsum[blockIdx.x] = s[255];
}

__global__ __launch_bounds__(128) void ecc_scan2(
    const unsigned* __restrict__ bsum, unsigned* __restrict__ bsumx)
{
    __shared__ unsigned s[128];
    const int t = threadIdx.x;
    unsigned v = (t < SCAN_BLOCKS) ? bsum[t] : 0u;
    s[t] = v; __syncthreads();
    #pragma unroll
    for (int d = 1; d < 128; d <<= 1) {
        unsigned add = (t >= d) ? s[t - d] : 0u;
        __syncthreads(); s[t] += add; __syncthreads();
    }
    if (t < SCAN_BLOCKS) bsumx[t] = s[t] - v;
}

__global__ __launch_bounds__(256) void ecc_scan3(
    unsigned* __restrict__ off, const unsigned* __restrict__ bsumx)
{
    int i = blockIdx.x * 256 + threadIdx.x;
    if (i < N_NODES) off[i] += bsumx[blockIdx.x];
    if (i == 0) off[N_NODES] = N_EDGES;
}

__global__ __launch_bounds__(256) void ecc_perm(
    const int* __restrict__ dst, const unsigned* __restrict__ off,
    const unsigned* __restrict__ rank, unsigned* __restrict__ perm)
{
    int e = blockIdx.x * 256 + threadIdx.x;
    if (e < N_EDGES) perm[off[dst[e]] + rank[e]] = (unsigned)e;
}

// ---------------- fused: MLP + dynamic-filter GEMM, register-pipelined B ---
// B-fragments double-buffered in two STATIC register sets (BA/BB); loads for
// chunk c+1 issued before compute of chunk c, pinned by sched_barrier(0).
// No LDS staging for B, no K-loop barriers.
__global__ __launch_bounds__(256, 2) void ecc_fused(
    const float* __restrict__ x,   const float* __restrict__ ea,
    const float* __restrict__ W1,  const float* __restrict__ b1,
    const unsigned short* __restrict__ w2s, const float* __restrict__ b2,
    const unsigned short* __restrict__ w3s,
    const int* __restrict__ src,   const unsigned* __restrict__ perm,
    unsigned* __restrict__ msg32)
{
    __shared__ __align__(16) unsigned short sm[256 * H2];   // 64KB h1s/h2s

    const int t = threadIdx.x;
    const int tile = blockIdx.x * 256;
    const int slot = tile + t;
    const bool ev = (slot < N_EDGES);
    const unsigned je = ev ? perm[slot] : 0u;

    const int w = t >> 6, l = t & 63, lr = l & 15, kg = l >> 4;

    // ---------------- phase 0a: L1 on VALU -> h1s (fp16, swizzled) ----------
    {
        float a[ED];
        #pragma unroll
        for (int c = 0; c < ED; ++c) a[c] = ev ? ea[(long)je * ED + c] : 0.f;

        float h1[H1];
        #pragma unroll
        for (int o = 0; o < H1; ++o) {
            float acc = b1[o];
            #pragma unroll
            for (int c = 0; c < ED; ++c) acc = fmaf(W1[o * ED + c], a[c], acc);
            h1[o] = fmaxf(acc, 0.f);
        }
        #pragma unroll
        for (int q = 0; q < 8; ++q) {
            u32x4 pk;
            #pragma unroll
            for (int j = 0; j < 4; ++j)
                pk[j] = pkrtz(h1[q*8 + 2*j], h1[q*8 + 2*j + 1]);
            const int boff = (t * 128 + q * 16) ^ ((t & 7) << 4);
            *(u32x4*)((char*)sm + boff) = pk;
        }
    }

    // ---------------- per-lane xs gather -> packed fp16 pairs ---------------
    unsigned xsh[4][4];
    #pragma unroll
    for (int mt = 0; mt < 4; ++mt) {
        const int er = tile + w * 64 + mt * 16 + lr;
        if (er < N_EDGES) {
            const float4* xp = (const float4*)(x + (long)src[perm[er]] * 32 + kg * 8);
            float4 v0 = xp[0], v1 = xp[1];
            xsh[mt][0] = pkrtz(v0.x, v0.y); xsh[mt][1] = pkrtz(v0.z, v0.w);
            xsh[mt][2] = pkrtz(v1.x, v1.y); xsh[mt][3] = pkrtz(v1.z, v1.w);
        } else {
            xsh[mt][0] = xsh[mt][1] = xsh[mt][2] = xsh[mt][3] = 0u;
        }
    }

    __syncthreads();

    // ---------------- phase 0b: layer 2 via MFMA (fp16) ---------------------
    {
        F16x8U hb[4][2];
        #pragma unroll
        for (int ne = 0; ne < 4; ++ne) {
            const int er = w * 64 + ne * 16 + lr;
            #pragma unroll
            for (int ks = 0; ks < 2; ++ks) {
                const int boff = (er * 128 + ks * 64 + kg * 16) ^ ((er & 7) << 4);
                hb[ne][ks].u = *(const u32x4*)((const char*)sm + boff);
            }
        }
        __syncthreads();   // all h1 reads complete before h2 overwrites

        #pragma unroll
        for (int mo = 0; mo < 8; ++mo) {
            F16x8U a2[2];
            #pragma unroll
            for (int ks = 0; ks < 2; ++ks)
                a2[ks].u = *(const u32x4*)(w2s + (mo*16 + lr) * 64 + ks*32 + kg*8);
            const float4 bv = *(const float4*)(b2 + mo*16 + kg*4);
            #pragma unroll
            for (int ne = 0; ne < 4; ++ne) {
                f32x4 c = (f32x4){0.f, 0.f, 0.f, 0.f};
                c = mfma16(a2[0].h, hb[ne][0].h, c);
                c = mfma16(a2[1].h, hb[ne][1].h, c);
                const unsigned p0 = pkrtz(fmaxf(c[0]+bv.x, 0.f), fmaxf(c[1]+bv.y, 0.f));
                const unsigned p1 = pkrtz(fmaxf(c[2]+bv.z, 0.f), fmaxf(c[3]+bv.w, 0.f));
                const int er = w * 64 + ne * 16 + lr;
                const int boff = (er * 256 + (mo*16 + kg*4) * 2) ^ ((er & 7) << 4);
                *(u32x2*)((char*)sm + boff) = (u32x2){p0, p1};
            }
        }
    }

    f32x4 acc[4][2];
    #pragma unroll
    for (int mt = 0; mt < 4; ++mt)
        #pragma unroll
        for (int nt = 0; nt < 2; ++nt) acc[mt][nt] = (f32x4){0.f,0.f,0.f,0.f};

    // per-lane B base pointers (row-major w3s)
    const char* gb0 = (const char*)w3s + lr * ROWB + kg * 16;
    const char* gb1 = gb0 + 16 * ROWB;

    __syncthreads();   // h2s ready; no more barriers

    // ---------------- K loop: 33 chunks, register double-buffered B ---------
    // chunk c covers ksteps c*4..c*4+3 (bytes c*256 + kk*64 in each row).
    F16x8U BA0[4], BA1[4], BB0[4], BB1[4];

#define LOADB(S0, S1, c) do {                                              \
        const char* _p0 = gb0 + (c) * 256;                                 \
        const char* _p1 = gb1 + (c) * 256;                                 \
        S0[0].u = *(const u32x4*)(_p0);       S0[1].u = *(const u32x4*)(_p0 + 64);  \
        S0[2].u = *(const u32x4*)(_p0 + 128); S0[3].u = *(const u32x4*)(_p0 + 192); \
        S1[0].u = *(const u32x4*)(_p1);       S1[1].u = *(const u32x4*)(_p1 + 64);  \
        S1[2].u = *(const u32x4*)(_p1 + 128); S1[3].u = *(const u32x4*)(_p1 + 192); \
    } while (0)

#define COMPUTE(S0, S1, c) do {                                            \
        u32x2 hv[4];                                                       \
        _Pragma("unroll")                                                  \
        for (int mt = 0; mt < 4; ++mt) {                                   \
            const int row = w * 64 + mt * 16 + lr;                         \
            const int boff = (row * 256 + (c) * 8) ^ ((row & 7) << 4);     \
            hv[mt] = *(const u32x2*)((const char*)sm + boff);              \
        }                                                                  \
        _Pragma("unroll")                                                  \
        for (int kk = 0; kk < 4; ++kk) {                                   \
            _Pragma("unroll")                                              \
            for (int mt = 0; mt < 4; ++mt) {                               \
                const unsigned h01 = hv[mt][kk >> 1];                      \
                F16x8U af;                                                 \
                if (kk & 1) {                                              \
                    af.u[0] = pk_mul_bhi(h01, xsh[mt][0]);                 \
                    af.u[1] = pk_mul_bhi(h01, xsh[mt][1]);                 \
                    af.u[2] = pk_mul_bhi(h01, xsh[mt][2]);                 \
                    af.u[3] = pk_mul_bhi(h01, xsh[mt][3]);                 \
                } else {                                                   \
                    af.u[0] = pk_mul_blo(h01, xsh[mt][0]);                 \
                    af.u[1] = pk_mul_blo(h01, xsh[mt][1]);                 \
                    af.u[2] = pk_mul_blo(h01, xsh[mt][2]);                 \
                    af.u[3] = pk_mul_blo(h01, xsh[mt][3]);                 \
                }                                                          \
                acc[mt][0] = mfma16(af.h, S0[kk].h, acc[mt][0]);           \
                acc[mt][1] = mfma16(af.h, S1[kk].h, acc[mt][1]);           \
            }                                                              \
        }                                                                  \
    } while (0)

    LOADB(BA0, BA1, 0);
    #pragma unroll 1
    for (int c = 0; c < 32; c += 2) {
        LOADB(BB0, BB1, c + 1);
        __builtin_amdgcn_sched_barrier(0);
        COMPUTE(BA0, BA1, c);
        __builtin_amdgcn_sched_barrier(0);
        LOADB(BA0, BA1, c + 2);              // c=30 loads chunk 32 (b3 tail)
        __builtin_amdgcn_sched_barrier(0);
        COMPUTE(BB0, BB1, c + 1);
        __builtin_amdgcn_sched_barrier(0);
    }
    {   // chunk 32, kstep 128 only (b3): A = fp16(xs); ksteps 129-131 are zero pad
        #pragma unroll
        for (int mt = 0; mt < 4; ++mt) {
            F16x8U af;
            af.u = (u32x4){xsh[mt][0], xsh[mt][1], xsh[mt][2], xsh[mt][3]};
            acc[mt][0] = mfma16(af.h, BA0[0].h, acc[mt][0]);
            acc[mt][1] = mfma16(af.h, BA1[0].h, acc[mt][1]);
        }
    }
#undef LOADB
#undef COMPUTE

    // ---------------- epilogue: packed fp16 msg store, slot order -----------
    // C layout: col = lane&15 -> o pair (2*lr, 2*lr+1), row = kg*4 + r
    #pragma unroll
    for (int mt = 0; mt < 4; ++mt) {
        #pragma unroll
        for (int r = 0; r < 4; ++r) {
            const int j = tile + w * 64 + mt * 16 + kg * 4 + r;
            if (j < N_EDGES)
                msg32[(long)j * 16 + lr] = pkrtz(acc[mt][0][r], acc[mt][1][r]);
        }
    }
}

// ---------------- gather-mean + relu (slot-contiguous rows) ----------------
__global__ __launch_bounds__(256) void ecc_gather(
    const unsigned* __restrict__ msg32, const unsigned* __restrict__ off,
    float* __restrict__ out)
{
    const int t = threadIdx.x;
    const int q = t & 15;                      // o-pair: o = 2q, 2q+1
    const int n = blockIdx.x * 16 + (t >> 4);
    if (n >= N_NODES) return;
    const unsigned lo = off[n], hi = off[n + 1];
    float s0 = 0.f, s1 = 0.f;
    for (unsigned j = lo; j < hi; ++j) {
        F16x2U v; v.u = msg32[(long)j * 16 + q];
        s0 += (float)v.h[0];
        s1 += (float)v.h[1];
    }
    const float dg = fmaxf((float)(hi - lo), 1.f);
    ((float2*)(out + (long)n * 32))[q] =
        make_float2(fmaxf(s0 / dg, 0.f), fmaxf(s1 / dg, 0.f));
}

extern "C" void kernel_launch(void* const* d_in, const int* in_sizes, int n_in,
                              void* d_out, int out_size, void* d_ws, size_t ws_size,
                              hipStream_t stream) {
    const float* x   = (const float*)d_in[0];
    const float* ea  = (const float*)d_in[1];
    const float* W1  = (const float*)d_in[2];
    const float* b1  = (const float*)d_in[3];
    const float* W2  = (const float*)d_in[4];
    const float* b2  = (const float*)d_in[5];
    const float* W3  = (const float*)d_in[6];
    const float* b3  = (const float*)d_in[7];
    const int*   src = (const int*)d_in[8];
    const int*   dst = (const int*)d_in[9];
    float* out = (float*)d_out;

    char* p = (char*)d_ws;
    unsigned short* w3s = (unsigned short*)p; p += W3S_USHORTS * 2;  // 270336
    unsigned short* w2s = (unsigned short*)p; p += 16384;
    unsigned* cnt   = (unsigned*)p; p += 100096;
    unsigned* off   = (unsigned*)p; p += 100352;
    unsigned* bsum  = (unsigned*)p; p += 512;
    unsigned* bsumx = (unsigned*)p; p += 512;
    unsigned* rank  = (unsigned*)p; p += 1000192;
    unsigned* perm  = (unsigned*)p; p += 1000192;
    unsigned* msg32 = (unsigned*)p;                                  // 16MB

    ecc_init<<<(W3S_USHORTS + 255) / 256, 256, 0, stream>>>(W3, b3, W2, cnt, w3s, w2s);
    ecc_hist<<<NBLK, 256, 0, stream>>>(dst, cnt, rank);
    ecc_scan1<<<SCAN_BLOCKS, 256, 0, stream>>>(cnt, off, bsum);
    ecc_scan2<<<1, 128, 0, stream>>>(bsum, bsumx);
    ecc_scan3<<<SCAN_BLOCKS, 256, 0, stream>>>(off, bsumx);
    ecc_perm<<<NBLK, 256, 0, stream>>>(dst, off, rank, perm);
    ecc_fused<<<NBLK, 256, 0, stream>>>(x, ea, W1, b1, w2s, b2, w3s, src, perm, msg32);
    ecc_gather<<<(N_NODES + 15) / 16, 256, 0, stream>>>(msg32, off, out);
}

// Round 12
// 125.834 us; speedup vs baseline: 1.4987x; 1.4987x over previous
//
#include <hip/hip_runtime.h>
#include <hip/hip_fp16.h>

#define N_NODES 25000
#define N_EDGES 250000
#define ED 6
#define H1 64
#define H2 128
#define NBLK 977                   // ceil(250000/256)
#define NCHUNK 33                  // 33 chunks x 4 ksteps = 132 (128 h2*xs + 1 b3 + 3 pad)
#define CHUNK_USH 4096             // per chunk: [kk=4][j=2][lane=64][8 ush]
#define W3S_USHORTS (NCHUNK*CHUNK_USH)   // 135168 ush = 264KB, L2-resident
#define W2S_USHORTS (H2*H1)
#define SCAN_BLOCKS 98

typedef float f32x4 __attribute__((ext_vector_type(4)));
typedef _Float16 f16x8 __attribute__((ext_vector_type(8)));
typedef _Float16 f16x2 __attribute__((ext_vector_type(2)));
typedef __fp16 fp16x2 __attribute__((ext_vector_type(2)));
typedef unsigned int u32x4 __attribute__((ext_vector_type(4)));
typedef unsigned int u32x2 __attribute__((ext_vector_type(2)));

union F16x8U { u32x4 u; f16x8 h; };
union F16x2U { unsigned u; f16x2 h; };
union PKU    { fp16x2 p; unsigned u; };

__device__ __forceinline__ unsigned pkrtz(float lo, float hi) {
    PKU r; r.p = __builtin_amdgcn_cvt_pkrtz(lo, hi); return r.u;
}
// d = (h.lo * x.lo, h.lo * x.hi)
__device__ __forceinline__ unsigned pk_mul_blo(unsigned h, unsigned x) {
    unsigned d;
    asm("v_pk_mul_f16 %0, %1, %2 op_sel:[0,0] op_sel_hi:[0,1]" : "=v"(d) : "v"(h), "v"(x));
    return d;
}
// d = (h.hi * x.lo, h.hi * x.hi)
__device__ __forceinline__ unsigned pk_mul_bhi(unsigned h, unsigned x) {
    unsigned d;
    asm("v_pk_mul_f16 %0, %1, %2 op_sel:[1,0] op_sel_hi:[1,1]" : "=v"(d) : "v"(h), "v"(x));
    return d;
}
__device__ __forceinline__ f32x4 mfma16(f16x8 a, f16x8 b, f32x4 c) {
    return __builtin_amdgcn_mfma_f32_16x16x32_f16(a, b, c, 0, 0, 0);
}
__device__ __forceinline__ void gload16(const void* g, void* l) {
    __builtin_amdgcn_global_load_lds(
        (const __attribute__((address_space(1))) unsigned int*)g,
        (__attribute__((address_space(3))) unsigned int*)l, 16, 0, 0);
}

// ---------------- init: zero cnt + repack W3(+b3)->fp16 lane-ordered, W2->fp16
// w3s chunk c, ush offset r = kk*1024 + j*512 + lane*8 + m holds:
//   B-row p = j*16 + (lane&15)  [-> output o = ((p&15)<<1)+(p>>4)]
//   GEMM-K index kp = (c*4+kk)*32 + (lane>>4)*8 + m
//   kp = k*32+i (k<128); [4096,4128) = b3; else zero pad.
// K-loop ds_read_b128 then hits base + lane*16 — bank-conflict-free.
__global__ __launch_bounds__(256) void ecc_init(
    const float* __restrict__ W3, const float* __restrict__ b3,
    const float* __restrict__ W2,
    unsigned* __restrict__ cnt, unsigned short* __restrict__ w3s,
    unsigned short* __restrict__ w2s)
{
    int idx = blockIdx.x * 256 + threadIdx.x;
    if (idx < W3S_USHORTS) {
        int c = idx >> 12, r = idx & 4095;
        int kk = r >> 10;
        int j  = (r >> 9) & 1;
        int lane = (r >> 3) & 63;
        int m  = r & 7;
        int p  = j * 16 + (lane & 15);
        int o  = ((p & 15) << 1) + (p >> 4);
        int kp = (c * 4 + kk) * 32 + (lane >> 4) * 8 + m;
        float v = 0.f;
        if (kp < 4096)      { int k = kp >> 5, i = kp & 31; v = W3[(o * 32 + i) * 128 + k]; }
        else if (kp < 4128) { v = b3[o * 32 + (kp - 4096)]; }
        __half hv = __float2half_rn(v);
        w3s[idx] = *reinterpret_cast<unsigned short*>(&hv);
    }
    if (idx < W2S_USHORTS) {
        __half hv = __float2half_rn(W2[idx]);
        w2s[idx] = *reinterpret_cast<unsigned short*>(&hv);
    }
    if (idx < N_NODES) cnt[idx] = 0u;
}

// ---------------- sort machinery -------------------------------------------
__global__ __launch_bounds__(256) void ecc_hist(
    const int* __restrict__ dst, unsigned* __restrict__ cnt,
    unsigned* __restrict__ rank)
{
    int e = blockIdx.x * 256 + threadIdx.x;
    if (e < N_EDGES) rank[e] = atomicAdd(&cnt[dst[e]], 1u);
}

__global__ __launch_bounds__(256) void ecc_scan1(
    const unsigned* __restrict__ cnt, unsigned* __restrict__ off,
    unsigned* __restrict__ bsum)
{
    __shared__ unsigned s[256];
    const int t = threadIdx.x, i = blockIdx.x * 256 + t;
    unsigned v = (i < N_NODES) ? cnt[i] : 0u;
    s[t] = v; __syncthreads();
    #pragma unroll
    for (int d = 1; d < 256; d <<= 1) {
        unsigned add = (t >= d) ? s[t - d] : 0u;
        __syncthreads(); s[t] += add; __syncthreads();
    }
    if (i < N_NODES) off[i] = s[t] - v;
    if (t == 255) bsum[blockIdx.x] = s[255];
}

__global__ __launch_bounds__(128) void ecc_scan2(
    const unsigned* __restrict__ bsum, unsigned* __restrict__ bsumx)
{
    __shared__ unsigned s[128];
    const int t = threadIdx.x;
    unsigned v = (t < SCAN_BLOCKS) ? bsum[t] : 0u;
    s[t] = v; __syncthreads();
    #pragma unroll
    for (int d = 1; d < 128; d <<= 1) {
        unsigned add = (t >= d) ? s[t - d] : 0u;
        __syncthreads(); s[t] += add; __syncthreads();
    }
    if (t < SCAN_BLOCKS) bsumx[t] = s[t] - v;
}

__global__ __launch_bounds__(256) void ecc_scan3(
    unsigned* __restrict__ off, const unsigned* __restrict__ bsumx)
{
    int i = blockIdx.x * 256 + threadIdx.x;
    if (i < N_NODES) off[i] += bsumx[blockIdx.x];
    if (i == 0) off[N_NODES] = N_EDGES;
}

__global__ __launch_bounds__(256) void ecc_perm(
    const int* __restrict__ dst, const unsigned* __restrict__ off,
    const unsigned* __restrict__ rank, unsigned* __restrict__ perm)
{
    int e = blockIdx.x * 256 + threadIdx.x;
    if (e < N_EDGES) perm[off[dst[e]] + rank[e]] = (unsigned)e;
}

// ---------------- fused: MLP (L1 VALU, L2 MFMA) + dynamic-filter GEMM ------
// Round-10 structure (async LDS double-buffer for B) with (a) lane-ordered
// conflict-free wbuf layout, (b) waves_per_eu(2,2) to unlock VGPR budget.
__global__ __launch_bounds__(256)
__attribute__((amdgpu_waves_per_eu(2, 2)))
void ecc_fused(
    const float* __restrict__ x,   const float* __restrict__ ea,
    const float* __restrict__ W1,  const float* __restrict__ b1,
    const unsigned short* __restrict__ w2s, const float* __restrict__ b2,
    const unsigned short* __restrict__ w3s,
    const int* __restrict__ src,   const unsigned* __restrict__ perm,
    unsigned* __restrict__ msg32)
{
    __shared__ __align__(16) unsigned short sm[256 * H2];       // 64KB h1s/h2s
    __shared__ __align__(16) unsigned short wbuf[2][CHUNK_USH]; // 2 x 8KB B-chunks

    const int t = threadIdx.x;
    const int tile = blockIdx.x * 256;
    const int slot = tile + t;
    const bool ev = (slot < N_EDGES);
    const unsigned je = ev ? perm[slot] : 0u;

    const int w = t >> 6, l = t & 63, lr = l & 15, kg = l >> 4;

    // stage chunk 0 now — DMA overlaps the whole MLP phase
    gload16(w3s + t * 8,        &wbuf[0][t * 8]);
    gload16(w3s + 2048 + t * 8, &wbuf[0][2048 + t * 8]);

    // ---------------- phase 0a: L1 on VALU -> h1s (fp16, swizzled) ----------
    {
        float a[ED];
        #pragma unroll
        for (int c = 0; c < ED; ++c) a[c] = ev ? ea[(long)je * ED + c] : 0.f;

        float h1[H1];
        #pragma unroll
        for (int o = 0; o < H1; ++o) {
            float acc = b1[o];
            #pragma unroll
            for (int c = 0; c < ED; ++c) acc = fmaf(W1[o * ED + c], a[c], acc);
            h1[o] = fmaxf(acc, 0.f);
        }
        #pragma unroll
        for (int q = 0; q < 8; ++q) {
            u32x4 pk;
            #pragma unroll
            for (int j = 0; j < 4; ++j)
                pk[j] = pkrtz(h1[q*8 + 2*j], h1[q*8 + 2*j + 1]);
            const int boff = (t * 128 + q * 16) ^ ((t & 7) << 4);
            *(u32x4*)((char*)sm + boff) = pk;
        }
    }

    // ---------------- per-lane xs gather -> packed fp16 pairs ---------------
    unsigned xsh[4][4];
    #pragma unroll
    for (int mt = 0; mt < 4; ++mt) {
        const int er = tile + w * 64 + mt * 16 + lr;
        if (er < N_EDGES) {
            const float4* xp = (const float4*)(x + (long)src[perm[er]] * 32 + kg * 8);
            float4 v0 = xp[0], v1 = xp[1];
            xsh[mt][0] = pkrtz(v0.x, v0.y); xsh[mt][1] = pkrtz(v0.z, v0.w);
            xsh[mt][2] = pkrtz(v1.x, v1.y); xsh[mt][3] = pkrtz(v1.z, v1.w);
        } else {
            xsh[mt][0] = xsh[mt][1] = xsh[mt][2] = xsh[mt][3] = 0u;
        }
    }

    // ---------------- phase 0b: layer 2 via MFMA (fp16) ---------------------
    {
        F16x8U hb[4][2];
        #pragma unroll
        for (int ne = 0; ne < 4; ++ne) {
            const int er = w * 64 + ne * 16 + lr;
            #pragma unroll
            for (int ks = 0; ks < 2; ++ks) {
                const int boff = (er * 128 + ks * 64 + kg * 16) ^ ((er & 7) << 4);
                hb[ne][ks].u = *(const u32x4*)((const char*)sm + boff);
            }
        }
        __syncthreads();   // all h1 reads complete before h2 overwrites

        #pragma unroll
        for (int mo = 0; mo < 8; ++mo) {
            F16x8U a2[2];
            #pragma unroll
            for (int ks = 0; ks < 2; ++ks)
                a2[ks].u = *(const u32x4*)(w2s + (mo*16 + lr) * 64 + ks*32 + kg*8);
            const float4 bv = *(const float4*)(b2 + mo*16 + kg*4);
            #pragma unroll
            for (int ne = 0; ne < 4; ++ne) {
                f32x4 c = (f32x4){0.f, 0.f, 0.f, 0.f};
                c = mfma16(a2[0].h, hb[ne][0].h, c);
                c = mfma16(a2[1].h, hb[ne][1].h, c);
                const unsigned p0 = pkrtz(fmaxf(c[0]+bv.x, 0.f), fmaxf(c[1]+bv.y, 0.f));
                const unsigned p1 = pkrtz(fmaxf(c[2]+bv.z, 0.f), fmaxf(c[3]+bv.w, 0.f));
                const int er = w * 64 + ne * 16 + lr;
                const int boff = (er * 256 + (mo*16 + kg*4) * 2) ^ ((er & 7) << 4);
                *(u32x2*)((char*)sm + boff) = (u32x2){p0, p1};
            }
        }
    }

    f32x4 acc[4][2];
    #pragma unroll
    for (int mt = 0; mt < 4; ++mt)
        #pragma unroll
        for (int nt = 0; nt < 2; ++nt) acc[mt][nt] = (f32x4){0.f,0.f,0.f,0.f};

    __syncthreads();   // h2s ready; chunk-0 DMA drained by this barrier

    // ---------------- K loop: 32 chunks + b3 tail, double-buffered ----------
    // Per chunk kk: b0 at byte kk*2048 + l*16, b1 at +1024 (lane-ordered,
    // conflict-free ds_read_b128).
    int cur = 0;
    #pragma unroll 1
    for (int c = 0; c < 32; ++c) {
        {   // stage next chunk into the other buffer
            const unsigned short* gs = w3s + (c + 1) * CHUNK_USH + t * 8;
            gload16(gs,        &wbuf[cur ^ 1][t * 8]);
            gload16(gs + 2048, &wbuf[cur ^ 1][2048 + t * 8]);
        }
        const char* wb = (const char*)wbuf[cur] + l * 16;

        u32x2 hv[4];   // 4 h2 values (fp16) per m-tile for this chunk
        #pragma unroll
        for (int mt = 0; mt < 4; ++mt) {
            const int row = w * 64 + mt * 16 + lr;
            const int boff = (row * 256 + c * 8) ^ ((row & 7) << 4);
            hv[mt] = *(const u32x2*)((const char*)sm + boff);
        }
        #pragma unroll
        for (int kk = 0; kk < 4; ++kk) {
            F16x8U b0, b1;
            b0.u = *(const u32x4*)(wb + kk * 2048);
            b1.u = *(const u32x4*)(wb + kk * 2048 + 1024);
            #pragma unroll
            for (int mt = 0; mt < 4; ++mt) {
                const unsigned h01 = hv[mt][kk >> 1];
                F16x8U af;
                if (kk & 1) {
                    af.u[0] = pk_mul_bhi(h01, xsh[mt][0]);
                    af.u[1] = pk_mul_bhi(h01, xsh[mt][1]);
                    af.u[2] = pk_mul_bhi(h01, xsh[mt][2]);
                    af.u[3] = pk_mul_bhi(h01, xsh[mt][3]);
                } else {
                    af.u[0] = pk_mul_blo(h01, xsh[mt][0]);
                    af.u[1] = pk_mul_blo(h01, xsh[mt][1]);
                    af.u[2] = pk_mul_blo(h01, xsh[mt][2]);
                    af.u[3] = pk_mul_blo(h01, xsh[mt][3]);
                }
                acc[mt][0] = mfma16(af.h, b0.h, acc[mt][0]);
                acc[mt][1] = mfma16(af.h, b1.h, acc[mt][1]);
            }
        }
        __syncthreads();   // drains this wave's DMA + all waves done with wb
        cur ^= 1;
    }
    {   // b3 tail (chunk 32, kstep 128 only): A = fp16(xs)
        const char* wb = (const char*)wbuf[cur] + l * 16;
        F16x8U b0, b1;
        b0.u = *(const u32x4*)(wb);
        b1.u = *(const u32x4*)(wb + 1024);
        #pragma unroll
        for (int mt = 0; mt < 4; ++mt) {
            F16x8U af;
            af.u = (u32x4){xsh[mt][0], xsh[mt][1], xsh[mt][2], xsh[mt][3]};
            acc[mt][0] = mfma16(af.h, b0.h, acc[mt][0]);
            acc[mt][1] = mfma16(af.h, b1.h, acc[mt][1]);
        }
    }

    // ---------------- epilogue: packed fp16 msg store, slot order -----------
    // C layout: col = lane&15 -> o pair (2*lr, 2*lr+1), row = kg*4 + r
    #pragma unroll
    for (int mt = 0; mt < 4; ++mt) {
        #pragma unroll
        for (int r = 0; r < 4; ++r) {
            const int j = tile + w * 64 + mt * 16 + kg * 4 + r;
            if (j < N_EDGES)
                msg32[(long)j * 16 + lr] = pkrtz(acc[mt][0][r], acc[mt][1][r]);
        }
    }
}

// ---------------- gather-mean + relu (slot-contiguous rows) ----------------
__global__ __launch_bounds__(256) void ecc_gather(
    const unsigned* __restrict__ msg32, const unsigned* __restrict__ off,
    float* __restrict__ out)
{
    const int t = threadIdx.x;
    const int q = t & 15;                      // o-pair: o = 2q, 2q+1
    const int n = blockIdx.x * 16 + (t >> 4);
    if (n >= N_NODES) return;
    const unsigned lo = off[n], hi = off[n + 1];
    float s0 = 0.f, s1 = 0.f;
    for (unsigned j = lo; j < hi; ++j) {
        F16x2U v; v.u = msg32[(long)j * 16 + q];
        s0 += (float)v.h[0];
        s1 += (float)v.h[1];
    }
    const float dg = fmaxf((float)(hi - lo), 1.f);
    ((float2*)(out + (long)n * 32))[q] =
        make_float2(fmaxf(s0 / dg, 0.f), fmaxf(s1 / dg, 0.f));
}

extern "C" void kernel_launch(void* const* d_in, const int* in_sizes, int n_in,
                              void* d_out, int out_size, void* d_ws, size_t ws_size,
                              hipStream_t stream) {
    const float* x   = (const float*)d_in[0];
    const float* ea  = (const float*)d_in[1];
    const float* W1  = (const float*)d_in[2];
    const float* b1  = (const float*)d_in[3];
    const float* W2  = (const float*)d_in[4];
    const float* b2  = (const float*)d_in[5];
    const float* W3  = (const float*)d_in[6];
    const float* b3  = (const float*)d_in[7];
    const int*   src = (const int*)d_in[8];
    const int*   dst = (const int*)d_in[9];
    float* out = (float*)d_out;

    char* p = (char*)d_ws;
    unsigned short* w3s = (unsigned short*)p; p += W3S_USHORTS * 2;  // 270336
    unsigned short* w2s = (unsigned short*)p; p += 16384;
    unsigned* cnt   = (unsigned*)p; p += 100096;
    unsigned* off   = (unsigned*)p; p += 100352;
    unsigned* bsum  = (unsigned*)p; p += 512;
    unsigned* bsumx = (unsigned*)p; p += 512;
    unsigned* rank  = (unsigned*)p; p += 1000192;
    unsigned* perm  = (unsigned*)p; p += 1000192;
    unsigned* msg32 = (unsigned*)p;                                  // 16MB

    ecc_init<<<(W3S_USHORTS + 255) / 256, 256, 0, stream>>>(W3, b3, W2, cnt, w3s, w2s);
    ecc_hist<<<NBLK, 256, 0, stream>>>(dst, cnt, rank);
    ecc_scan1<<<SCAN_BLOCKS, 256, 0, stream>>>(cnt, off, bsum);
    ecc_scan2<<<1, 128, 0, stream>>>(bsum, bsumx);
    ecc_scan3<<<SCAN_BLOCKS, 256, 0, stream>>>(off, bsumx);
    ecc_perm<<<NBLK, 256, 0, stream>>>(dst, off, rank, perm);
    ecc_fused<<<NBLK, 256, 0, stream>>>(x, ea, W1, b1, w2s, b2, w3s, src, perm, msg32);
    ecc_gather<<<(N_NODES + 15) / 16, 256, 0, stream>>>(msg32, off, out);
}